// Round 14
// baseline (1167.428 us; speedup 1.0000x reference)
//
#include <hip/hip_runtime.h>

// Residual VQ, fully fused: all 8 stages in one kernel, 512-thread blocks.
// Residual tile persists in LDS. Distances: bf16 MFMA with A = hi+lo split
// (registers), B = hi only (halves LDS staging). Margin collection against a
// lagged shared running-min (register-local mins, sparse shfl updates), then
// exact-fp32-chain rescue. qout recovered by telescoping (x - r_final).
// NOTE round-13 lesson: launch_bounds min-waves=2 capped VGPR at 128 ->
// 1.5 GB scratch spill. LDS already limits to 1 block/CU, so min-waves=1
// (full 256-VGPR budget) costs nothing and eliminates the spill.
// x [B,N,D] fp32, codebooks [Q,C,D] fp32.
// d_out (flat fp32): qout [M*D], indices [M*Q] (as float), losses [Q]
typedef __attribute__((ext_vector_type(8))) short short8;
typedef __attribute__((ext_vector_type(4))) float f32x4;

constexpr int Bq = 8, Nn = 4096, Dd = 256, Qq = 8, Cc = 1024;
constexpr int Mm = Bq * Nn;        // 32768 tokens
constexpr int TOK = 64;            // tokens per block
constexpr int NT = 512;            // 8 waves: wave (tg,h) = 32 tokens x tiles h,h+4 per oct
constexpr int LCAP = 32;           // rescue list capacity per token
constexpr float MARGIN = 0.5f;     // >> 2*max|approx - fp32-chain| score error (sigma~0.02)

__device__ inline unsigned short f2bf(float f) {          // fp32 -> bf16 RNE
  unsigned u = __float_as_uint(f);
  unsigned r = (u + 0x7FFFu + ((u >> 16) & 1u)) >> 16;
  return (unsigned short)r;
}
__device__ inline float bf2f(unsigned short h) { return __uint_as_float(((unsigned)h) << 16); }
// order-preserving float<->uint for LDS atomicMin
__device__ inline unsigned fenc(float f) {
  unsigned u = __float_as_uint(f);
  return (u & 0x80000000u) ? ~u : (u | 0x80000000u);
}
__device__ inline float fdec(unsigned e) {
  unsigned u = (e & 0x80000000u) ? (e & 0x7fffffffu) : ~e;
  return __uint_as_float(u);
}

// ---------------------------------------------------------------------------
// prep: cnorm[q*C+c] = sum_d cb[q][c][d]^2 ; zero loss accumulators  (256 thr)
__global__ void prep_kernel(const float* __restrict__ cbs,
                            float* __restrict__ cnorm,
                            float* __restrict__ loss_acc) {
  const int wave = threadIdx.x >> 6;
  const int lane = threadIdx.x & 63;
  const int row  = blockIdx.x * 4 + wave;            // 0 .. Q*C-1
  const float4* r4 = reinterpret_cast<const float4*>(cbs + (size_t)row * Dd);
  const float4 v = r4[lane];
  float s = v.x * v.x + v.y * v.y + v.z * v.z + v.w * v.w;
#pragma unroll
  for (int off = 32; off; off >>= 1) s += __shfl_down(s, off);
  if (lane == 0) cnorm[row] = s;
  if (blockIdx.x == 0 && threadIdx.x < Qq) loss_acc[threadIdx.x] = 0.0f;
}

// ---------------------------------------------------------------------------
// Build frag-major bf16-hi codebook: Bh[q][nt][ks][lane] (short8) =
// bf16(cb[q][ nt*16 + (lane&15) ][ ks*32 + (lane>>4)*8 + j ]), j=0..7.
__global__ __launch_bounds__(256)
void build_bfrag(const float* __restrict__ cbs, short* __restrict__ Bh) {
  const int q    = blockIdx.x >> 6;      // grid = Q*64
  const int nt   = blockIdx.x & 63;
  const int lane = threadIdx.x & 63;
  const int ks0  = threadIdx.x >> 6;     // 0..3
#pragma unroll
  for (int h = 0; h < 2; ++h) {
    const int ks = ks0 + h * 4;
    const int c  = nt * 16 + (lane & 15);
    const int k  = ks * 32 + (lane >> 4) * 8;
    const float* src = cbs + ((size_t)(q * Cc + c)) * Dd + k;
    short8 hi;
#pragma unroll
    for (int j = 0; j < 8; ++j) hi[j] = (short)f2bf(src[j]);
    ((short8*)Bh)[(((size_t)(q * 64 + nt) * 8 + ks) * 64 + lane)] = hi;
  }
}

// ---------------------------------------------------------------------------
// exact fp32-chain score from the swizzled LDS tile (bitwise-identical chain:
// ascending d4, components x,y,z,w, from 0.0f; unroll only batches loads).
__device__ float exact_score_lds(const float4* __restrict__ tile, int t, int sw,
                                 const float* __restrict__ cb,
                                 const float* __restrict__ cnorm, int cand) {
  const float4* cv = reinterpret_cast<const float4*>(cb + (size_t)cand * Dd);
  float a = 0.0f;
#pragma unroll 8
  for (int d4 = 0; d4 < 64; ++d4) {
    const float4 rv = tile[(t * 64 + d4) ^ sw];
    const float4 c4 = cv[d4];
    a += rv.x * c4.x; a += rv.y * c4.y; a += rv.z * c4.z; a += rv.w * c4.w;
  }
  return cnorm[cand] - 2.0f * a;
}

// ---------------------------------------------------------------------------
// fused kernel: grid = Mm/TOK = 512 blocks x 512 threads (8 waves).
__global__ __launch_bounds__(NT, 1)
void vq_fused(const float* __restrict__ cbs,     // [Q][C][D] fp32
              const short8* __restrict__ bh,     // frag-major bf16 hi (all stages)
              const float* __restrict__ cnorm,   // [Q][C]
              const float* __restrict__ x,       // [M][D]
              float* __restrict__ qout,          // [M][D]
              float* __restrict__ idx_out,       // [M][Q] indices as float
              float* __restrict__ loss_acc) {    // [Q]
  __shared__ short8 bbuf[8][8][64];              // 64 KB: one oct (8 N-tiles), hi only
  __shared__ float4 tile[TOK * 64];              // 64 KB fp32 residual (persistent)
  __shared__ float  cn_lds[Cc];                  // 4 KB
  __shared__ unsigned runm_sh[TOK];              // shared running min (encoded)
  __shared__ int cnt[TOK];
  __shared__ int list[TOK][LCAP];                // 8 KB
  __shared__ int win[TOK];

  const int tid  = threadIdx.x;
  const int lane = tid & 63;
  const int wv   = tid >> 6;                     // 0..7
  const int tg   = wv >> 2;                      // token group (32 tokens)
  const int h    = wv & 3;                       // tile slots h and h+4 in each oct
  const int tok0 = blockIdx.x * TOK;
  const int col  = lane & 15;                    // candidate col
  const int g4   = lane >> 4;                    // token rows g4*4 .. g4*4+3

  // ---- load x into the persistent residual tile (coalesced, swizzled)
  const float4* xs = reinterpret_cast<const float4*>(x + (size_t)tok0 * Dd);
#pragma unroll
  for (int k = 0; k < 8; ++k) {
    const int j = tid + k * NT;
    const int tk = j >> 6, d4 = j & 63;
    tile[(tk * 64 + d4) ^ (tk & 7)] = xs[j];
  }
  __syncthreads();

  // stage one oct (8 N-tiles, hi only = 64 KB): 64 chunks of 64 lanes x 16 B;
  // 8 waves -> 8 chunks per wave. LDS dst wave-uniform (HW appends lane*16).
  auto stage_oct = [&](const short8* bhq, int oct) {
#pragma unroll
    for (int i = 0; i < 8; ++i) {
      const int c  = wv * 8 + i;                 // 0..63
      const int t  = c >> 3, ks = c & 7;
      const short8* src = bhq + (((size_t)(oct * 8 + t)) * 8 + ks) * 64 + lane;
      short8* dst = &bbuf[t][ks][0];
      __builtin_amdgcn_global_load_lds(
          (const __attribute__((address_space(1))) void*)src,
          (__attribute__((address_space(3))) void*)dst, 16, 0, 0);
    }
  };

  stage_oct(bh, 0);                              // stage 0, oct 0

#pragma unroll 1
  for (int q = 0; q < Qq; ++q) {
    const float*  cb  = cbs + (size_t)q * Cc * Dd;
    const float*  cn_ = cnorm + (size_t)q * Cc;
    const short8* bhq = bh + (size_t)q * 32768;

    // ---- phase A: A-fragments hi+lo for the wave's 32 tokens (2 A-tiles).
    short8 ah0[8], al0[8], ah1[8], al1[8];
    {
      const int tk0 = tg * 32 + (lane & 15);
      const int tk1 = tk0 + 16;
#pragma unroll
      for (int ks = 0; ks < 8; ++ks) {
        const int d4 = ks * 8 + (lane >> 4) * 2;
        {
          const float4 f0 = tile[(tk0 * 64 + d4) ^ (tk0 & 7)];
          const float4 f1 = tile[(tk0 * 64 + d4 + 1) ^ (tk0 & 7)];
          const float v[8] = {f0.x, f0.y, f0.z, f0.w, f1.x, f1.y, f1.z, f1.w};
#pragma unroll
          for (int j = 0; j < 8; ++j) {
            const unsigned short hb = f2bf(v[j]);
            ah0[ks][j] = (short)hb;
            al0[ks][j] = (short)f2bf(v[j] - bf2f(hb));
          }
        }
        {
          const float4 f0 = tile[(tk1 * 64 + d4) ^ (tk1 & 7)];
          const float4 f1 = tile[(tk1 * 64 + d4 + 1) ^ (tk1 & 7)];
          const float v[8] = {f0.x, f0.y, f0.z, f0.w, f1.x, f1.y, f1.z, f1.w};
#pragma unroll
          for (int j = 0; j < 8; ++j) {
            const unsigned short hb = f2bf(v[j]);
            ah1[ks][j] = (short)hb;
            al1[ks][j] = (short)f2bf(v[j] - bf2f(hb));
          }
        }
      }
    }
    if (tid < TOK) { cnt[tid] = 0; runm_sh[tid] = fenc(3.4e38f); }
    if (tid < 256) {
      const float4* s4 = reinterpret_cast<const float4*>(cn_);
      reinterpret_cast<float4*>(cn_lds)[tid] = s4[tid];
    }

    float min8[2][4];                            // per-lane running min [a][r]
#pragma unroll
    for (int a = 0; a < 2; ++a)
#pragma unroll
      for (int r = 0; r < 4; ++r) min8[a][r] = 3.4e38f;

    // ---- phase B: 8 octs; wave computes tiles h and h+4 of each oct.
#pragma unroll 1
    for (int o = 0; o < 8; ++o) {
      __syncthreads();                           // oct o staged & inits visible

      f32x4 acc[2][2][2];                        // [jj][a][part], all static idx
#pragma unroll
      for (int jj = 0; jj < 2; ++jj)
#pragma unroll
        for (int a = 0; a < 2; ++a)
#pragma unroll
          for (int pp = 0; pp < 2; ++pp) acc[jj][a][pp] = (f32x4){0.f, 0.f, 0.f, 0.f};

#pragma unroll
      for (int jj = 0; jj < 2; ++jj) {
        const int jt = h + jj * 4;
#pragma unroll
        for (int ks = 0; ks < 8; ++ks) {
          const short8 vb = bbuf[jt][ks][lane];
          acc[jj][0][0] = __builtin_amdgcn_mfma_f32_16x16x32_bf16(ah0[ks], vb, acc[jj][0][0], 0, 0, 0);
          acc[jj][0][1] = __builtin_amdgcn_mfma_f32_16x16x32_bf16(al0[ks], vb, acc[jj][0][1], 0, 0, 0);
          acc[jj][1][0] = __builtin_amdgcn_mfma_f32_16x16x32_bf16(ah1[ks], vb, acc[jj][1][0], 0, 0, 0);
          acc[jj][1][1] = __builtin_amdgcn_mfma_f32_16x16x32_bf16(al1[ks], vb, acc[jj][1][1], 0, 0, 0);
        }
      }
      __syncthreads();                           // oct o consumed by all waves

      if (o + 1 < 8)       stage_oct(bhq, o + 1);
      else if (q + 1 < Qq) stage_oct(bhq + 32768, 0);
      // (loads fly under scoring/collection and phases C/D/A)

      // scores for this oct: s[jj][a][r]
      float s[2][2][4];
#pragma unroll
      for (int jj = 0; jj < 2; ++jj) {
        const float cn = cn_lds[(o * 8 + h + jj * 4) * 16 + col];
#pragma unroll
        for (int a = 0; a < 2; ++a)
#pragma unroll
          for (int r = 0; r < 4; ++r) {
            s[jj][a][r] = cn - 2.0f * (acc[jj][a][0][r] + acc[jj][a][1][r]);
            min8[a][r] = s[jj][a][r] < min8[a][r] ? s[jj][a][r] : min8[a][r];
          }
      }

      // sparse shared-min update (octs 0,3,7): 8 chains x 4 shfl steps
      if (o == 0 || o == 3 || o == 7) {
#pragma unroll
        for (int a = 0; a < 2; ++a)
#pragma unroll
          for (int r = 0; r < 4; ++r) {
            float v = min8[a][r];
#pragma unroll
            for (int m = 1; m < 16; m <<= 1) {
              const float ov = __shfl_xor(v, m);
              v = ov < v ? ov : v;
            }
            if (col == 0)
              atomicMin(&runm_sh[tg * 32 + a * 16 + g4 * 4 + r], fenc(v));
          }
      }

      // collect vs (possibly lagged) shared min: superset of the validated
      // prefix-min margin rule -> exact winner always collected.
#pragma unroll
      for (int jj = 0; jj < 2; ++jj)
#pragma unroll
        for (int a = 0; a < 2; ++a)
#pragma unroll
          for (int r = 0; r < 4; ++r) {
            const int t = tg * 32 + a * 16 + g4 * 4 + r;
            if (s[jj][a][r] <= fdec(runm_sh[t]) + MARGIN) {
              const int pos = atomicAdd(&cnt[t], 1);
              if (pos < LCAP) list[t][pos] = (o * 8 + h + jj * 4) * 16 + col;
            }
          }
    }
    __syncthreads();                             // lists complete

    // ---- phase C: parallel rescue — 8 threads per token, candidate-sliced.
    {
      const int t    = tid >> 3;
      const int slot = tid & 7;
      const int sw   = t & 7;
      const int c_   = cnt[t];
      float best = 3.4e38f;
      int   wdx  = 1 << 30;
      if (c_ == 1) {
        wdx = list[t][0];
        best = 0.0f;                             // uniform across the 8 slots
      } else if (c_ <= LCAP) {
        for (int it = slot; it < c_; it += 8) {
          const int cand = list[t][it];
          const float sc = exact_score_lds(tile, t, sw, cb, cn_, cand);
          if (sc < best || (sc == best && cand < wdx)) { best = sc; wdx = cand; }
        }
      } else {        // overflow safety net: full exact scan, candidate-sliced
        for (int cand = slot; cand < Cc; cand += 8) {
          const float sc = exact_score_lds(tile, t, sw, cb, cn_, cand);
          if (sc < best || (sc == best && cand < wdx)) { best = sc; wdx = cand; }
        }
      }
#pragma unroll
      for (int m = 1; m < 8; m <<= 1) {
        const float ov = __shfl_xor(best, m);
        const int   oi = __shfl_xor(wdx, m);
        if (ov < best || (ov == best && oi < wdx)) { best = ov; wdx = oi; }
      }
      if (slot == 0) {
        win[t] = wdx;
        idx_out[(size_t)(tok0 + t) * Qq + q] = (float)wdx;
      }
    }
    __syncthreads();

    // ---- phase D: epilogue — update residual tile in place + loss.
    //   e = q - r; q_st = r + e; r_new = r - q_st; loss += e^2
    float lsum = 0.0f;
    {
      const float4* cb4 = reinterpret_cast<const float4*>(cb);
#pragma unroll
      for (int k = 0; k < 8; ++k) {
        const int j = tid + k * NT;
        const int tk = j >> 6, d4 = j & 63;
        const int widx = win[tk];
        const float4 cv = cb4[(size_t)widx * 64 + d4];
        const float4 rv = tile[(tk * 64 + d4) ^ (tk & 7)];
        const float ex = cv.x - rv.x, ey = cv.y - rv.y, ez = cv.z - rv.z, ew = cv.w - rv.w;
        const float qsx = rv.x + ex, qsy = rv.y + ey, qsz = rv.z + ez, qsw = rv.w + ew;
        lsum += ex * ex + ey * ey + ez * ez + ew * ew;
        tile[(tk * 64 + d4) ^ (tk & 7)] =
            make_float4(rv.x - qsx, rv.y - qsy, rv.z - qsz, rv.w - qsw);
      }
    }
#pragma unroll
    for (int s = 32; s; s >>= 1) lsum += __shfl_xor(lsum, s);
    if (lane == 0) atomicAdd(&loss_acc[q], lsum);
    __syncthreads();     // tile updated before next stage / final out
  }

  // ---- final: qout = x - r_final (telescoped straight-through sum), coalesced
  {
    float4* qo = reinterpret_cast<float4*>(qout + (size_t)tok0 * Dd);
#pragma unroll
    for (int k = 0; k < 8; ++k) {
      const int j = tid + k * NT;
      const int tk = j >> 6, d4 = j & 63;
      const float4 xv = xs[j];
      const float4 rv = tile[(tk * 64 + d4) ^ (tk & 7)];
      qo[j] = make_float4(xv.x - rv.x, xv.y - rv.y, xv.z - rv.z, xv.w - rv.w);
    }
  }
}

// ---------------------------------------------------------------------------
__global__ void finalize_losses(const float* __restrict__ loss_acc,
                                float* __restrict__ loss_out) {
  if (threadIdx.x < Qq) loss_out[threadIdx.x] = loss_acc[threadIdx.x] * (1.0f / (float)(Mm * Dd));
}

extern "C" void kernel_launch(void* const* d_in, const int* in_sizes, int n_in,
                              void* d_out, int out_size, void* d_ws, size_t ws_size,
                              hipStream_t stream) {
  const float* x   = (const float*)d_in[0];   // [B,N,D]
  const float* cbs = (const float*)d_in[1];   // [Q,C,D]
  float* out      = (float*)d_out;
  float* qout     = out;                               // M*D
  float* idx_out  = out + (size_t)Mm * Dd;             // M*Q
  float* loss_out = idx_out + (size_t)Mm * Qq;         // Q

  char* w = (char*)d_ws;
  short* Bh       = (short*)w;                                  // 4 MB
  float* cnorm    = (float*)(w + (size_t)4194304);              // 32 KB
  float* loss_acc = (float*)(w + (size_t)4227072);              // 256 B

  prep_kernel<<<(Qq * Cc) / 4, 256, 0, stream>>>(cbs, cnorm, loss_acc);
  build_bfrag<<<Qq * 64, 256, 0, stream>>>(cbs, Bh);

  vq_fused<<<Mm / TOK, NT, 0, stream>>>(cbs, (const short8*)Bh,
                                        cnorm, x, qout, idx_out, loss_acc);

  finalize_losses<<<1, 64, 0, stream>>>(loss_acc, loss_out);
}

// Round 15
// 658.109 us; speedup vs baseline: 1.7739x; 1.7739x over previous
//
#include <hip/hip_runtime.h>

// Residual VQ, fully fused: all 8 stages in one kernel, 512-thread blocks.
// Residual tile persists in LDS. Distances: bf16 MFMA, A = hi+lo split in
// registers (16 tokens/wave -> 64 VGPRs, fits the 128-VGPR budget hipcc
// insists on for 512-thread kernels: rounds 13/14 proved 32 tokens/wave ->
// 128-reg A-frags -> 1.6 GB scratch spill), B = hi only (halves staging).
// Margin collection vs lagged shared running-min, exact-fp32-chain rescue,
// qout telescoped (x - r_final).
// x [B,N,D] fp32, codebooks [Q,C,D] fp32.
// d_out (flat fp32): qout [M*D], indices [M*Q] (as float), losses [Q]
typedef __attribute__((ext_vector_type(8))) short short8;
typedef __attribute__((ext_vector_type(4))) float f32x4;

constexpr int Bq = 8, Nn = 4096, Dd = 256, Qq = 8, Cc = 1024;
constexpr int Mm = Bq * Nn;        // 32768 tokens
constexpr int TOK = 64;            // tokens per block
constexpr int NT = 512;            // 8 waves: wave (tg,h) = 16 tokens x 4 tiles/oct
constexpr int LCAP = 32;           // rescue list capacity per token
constexpr float MARGIN = 0.5f;     // >> 2*max|approx - fp32-chain| score error

__device__ inline unsigned short f2bf(float f) {          // fp32 -> bf16 RNE
  unsigned u = __float_as_uint(f);
  unsigned r = (u + 0x7FFFu + ((u >> 16) & 1u)) >> 16;
  return (unsigned short)r;
}
__device__ inline float bf2f(unsigned short h) { return __uint_as_float(((unsigned)h) << 16); }
// order-preserving float<->uint for LDS atomicMin
__device__ inline unsigned fenc(float f) {
  unsigned u = __float_as_uint(f);
  return (u & 0x80000000u) ? ~u : (u | 0x80000000u);
}
__device__ inline float fdec(unsigned e) {
  unsigned u = (e & 0x80000000u) ? (e & 0x7fffffffu) : ~e;
  return __uint_as_float(u);
}

// ---------------------------------------------------------------------------
// prep: cnorm[q*C+c] = sum_d cb[q][c][d]^2 ; zero loss accumulators  (256 thr)
__global__ void prep_kernel(const float* __restrict__ cbs,
                            float* __restrict__ cnorm,
                            float* __restrict__ loss_acc) {
  const int wave = threadIdx.x >> 6;
  const int lane = threadIdx.x & 63;
  const int row  = blockIdx.x * 4 + wave;            // 0 .. Q*C-1
  const float4* r4 = reinterpret_cast<const float4*>(cbs + (size_t)row * Dd);
  const float4 v = r4[lane];
  float s = v.x * v.x + v.y * v.y + v.z * v.z + v.w * v.w;
#pragma unroll
  for (int off = 32; off; off >>= 1) s += __shfl_down(s, off);
  if (lane == 0) cnorm[row] = s;
  if (blockIdx.x == 0 && threadIdx.x < Qq) loss_acc[threadIdx.x] = 0.0f;
}

// ---------------------------------------------------------------------------
// Build frag-major bf16-hi codebook: Bh[q][nt][ks][lane] (short8) =
// bf16(cb[q][ nt*16 + (lane&15) ][ ks*32 + (lane>>4)*8 + j ]), j=0..7.
__global__ __launch_bounds__(256)
void build_bfrag(const float* __restrict__ cbs, short* __restrict__ Bh) {
  const int q    = blockIdx.x >> 6;      // grid = Q*64
  const int nt   = blockIdx.x & 63;
  const int lane = threadIdx.x & 63;
  const int ks0  = threadIdx.x >> 6;     // 0..3
#pragma unroll
  for (int h = 0; h < 2; ++h) {
    const int ks = ks0 + h * 4;
    const int c  = nt * 16 + (lane & 15);
    const int k  = ks * 32 + (lane >> 4) * 8;
    const float* src = cbs + ((size_t)(q * Cc + c)) * Dd + k;
    short8 hi;
#pragma unroll
    for (int j = 0; j < 8; ++j) hi[j] = (short)f2bf(src[j]);
    ((short8*)Bh)[(((size_t)(q * 64 + nt) * 8 + ks) * 64 + lane)] = hi;
  }
}

// ---------------------------------------------------------------------------
// exact fp32-chain score from the swizzled LDS tile (bitwise-identical chain:
// ascending d4, components x,y,z,w, from 0.0f; unroll only batches loads).
__device__ float exact_score_lds(const float4* __restrict__ tile, int t, int sw,
                                 const float* __restrict__ cb,
                                 const float* __restrict__ cnorm, int cand) {
  const float4* cv = reinterpret_cast<const float4*>(cb + (size_t)cand * Dd);
  float a = 0.0f;
#pragma unroll 8
  for (int d4 = 0; d4 < 64; ++d4) {
    const float4 rv = tile[(t * 64 + d4) ^ sw];
    const float4 c4 = cv[d4];
    a += rv.x * c4.x; a += rv.y * c4.y; a += rv.z * c4.z; a += rv.w * c4.w;
  }
  return cnorm[cand] - 2.0f * a;
}

// ---------------------------------------------------------------------------
// fused kernel: grid = Mm/TOK = 512 blocks x 512 threads (8 waves).
__global__ __launch_bounds__(NT, 1)
void vq_fused(const float* __restrict__ cbs,     // [Q][C][D] fp32
              const short8* __restrict__ bh,     // frag-major bf16 hi (all stages)
              const float* __restrict__ cnorm,   // [Q][C]
              const float* __restrict__ x,       // [M][D]
              float* __restrict__ qout,          // [M][D]
              float* __restrict__ idx_out,       // [M][Q] indices as float
              float* __restrict__ loss_acc) {    // [Q]
  __shared__ short8 bbuf[8][8][64];              // 64 KB: one oct (8 N-tiles), hi only
  __shared__ float4 tile[TOK * 64];              // 64 KB fp32 residual (persistent)
  __shared__ float  cn_lds[Cc];                  // 4 KB
  __shared__ unsigned runm_sh[TOK];              // shared running min (encoded)
  __shared__ int cnt[TOK];
  __shared__ int list[TOK][LCAP];                // 8 KB
  __shared__ int win[TOK];

  const int tid  = threadIdx.x;
  const int lane = tid & 63;
  const int wv   = tid >> 6;                     // 0..7
  const int tg   = wv >> 1;                      // token group (16 tokens), 0..3
  const int h    = wv & 1;                       // oct half: tiles h*4 .. h*4+3
  const int tok0 = blockIdx.x * TOK;
  const int col  = lane & 15;                    // candidate col
  const int g4   = lane >> 4;                    // token rows g4*4 .. g4*4+3

  // ---- load x into the persistent residual tile (coalesced, swizzled)
  const float4* xs = reinterpret_cast<const float4*>(x + (size_t)tok0 * Dd);
#pragma unroll
  for (int k = 0; k < 8; ++k) {
    const int j = tid + k * NT;
    const int tk = j >> 6, d4 = j & 63;
    tile[(tk * 64 + d4) ^ (tk & 7)] = xs[j];
  }
  __syncthreads();

  // stage one oct (8 N-tiles, hi only = 64 KB): 64 chunks of 64 lanes x 16 B;
  // 8 waves -> 8 chunks per wave. LDS dst wave-uniform (HW appends lane*16).
  auto stage_oct = [&](const short8* bhq, int oct) {
#pragma unroll
    for (int i = 0; i < 8; ++i) {
      const int c  = wv * 8 + i;                 // 0..63
      const int t  = c >> 3, ks = c & 7;
      const short8* src = bhq + (((size_t)(oct * 8 + t)) * 8 + ks) * 64 + lane;
      short8* dst = &bbuf[t][ks][0];
      __builtin_amdgcn_global_load_lds(
          (const __attribute__((address_space(1))) void*)src,
          (__attribute__((address_space(3))) void*)dst, 16, 0, 0);
    }
  };

  stage_oct(bh, 0);                              // stage 0, oct 0

#pragma unroll 1
  for (int q = 0; q < Qq; ++q) {
    const float*  cb  = cbs + (size_t)q * Cc * Dd;
    const float*  cn_ = cnorm + (size_t)q * Cc;
    const short8* bhq = bh + (size_t)q * 32768;

    // ---- phase A: A-fragments hi+lo for the wave's 16 tokens (64 VGPRs).
    short8 ah[8], al[8];
    {
      const int tk = tg * 16 + (lane & 15);
      const int sw = tk & 7;
#pragma unroll
      for (int ks = 0; ks < 8; ++ks) {
        const int d4 = ks * 8 + (lane >> 4) * 2;
        const float4 f0 = tile[(tk * 64 + d4) ^ sw];
        const float4 f1 = tile[(tk * 64 + d4 + 1) ^ sw];
        const float v[8] = {f0.x, f0.y, f0.z, f0.w, f1.x, f1.y, f1.z, f1.w};
#pragma unroll
        for (int j = 0; j < 8; ++j) {
          const unsigned short hb = f2bf(v[j]);
          ah[ks][j] = (short)hb;
          al[ks][j] = (short)f2bf(v[j] - bf2f(hb));
        }
      }
    }
    if (tid < TOK) { cnt[tid] = 0; runm_sh[tid] = fenc(3.4e38f); }
    if (tid < 256) {
      const float4* s4 = reinterpret_cast<const float4*>(cn_);
      reinterpret_cast<float4*>(cn_lds)[tid] = s4[tid];
    }

    float min8[4];                               // per-lane running min [r]
#pragma unroll
    for (int r = 0; r < 4; ++r) min8[r] = 3.4e38f;

    // ---- phase B: 8 octs; wave computes tiles h*4..h*4+3 of each oct
    // (two pairs, bounding accumulator liveness to 16 regs).
#pragma unroll 1
    for (int o = 0; o < 8; ++o) {
      __syncthreads();                           // oct o staged & inits visible

      float s[4][4];                             // [tile][r]
#pragma unroll
      for (int pair = 0; pair < 2; ++pair) {
        f32x4 acc[2][2];                         // [tile-in-pair][part]
#pragma unroll
        for (int tp = 0; tp < 2; ++tp)
#pragma unroll
          for (int pp = 0; pp < 2; ++pp) acc[tp][pp] = (f32x4){0.f, 0.f, 0.f, 0.f};
#pragma unroll
        for (int ks = 0; ks < 8; ++ks) {
#pragma unroll
          for (int tp = 0; tp < 2; ++tp) {
            const short8 vb = bbuf[h * 4 + pair * 2 + tp][ks][lane];
            acc[tp][0] = __builtin_amdgcn_mfma_f32_16x16x32_bf16(ah[ks], vb, acc[tp][0], 0, 0, 0);
            acc[tp][1] = __builtin_amdgcn_mfma_f32_16x16x32_bf16(al[ks], vb, acc[tp][1], 0, 0, 0);
          }
        }
#pragma unroll
        for (int tp = 0; tp < 2; ++tp) {
          const float cn = cn_lds[(o * 8 + h * 4 + pair * 2 + tp) * 16 + col];
#pragma unroll
          for (int r = 0; r < 4; ++r) {
            s[pair * 2 + tp][r] = cn - 2.0f * (acc[tp][0][r] + acc[tp][1][r]);
            min8[r] = s[pair * 2 + tp][r] < min8[r] ? s[pair * 2 + tp][r] : min8[r];
          }
        }
      }
      __syncthreads();                           // oct o consumed by all waves

      if (o + 1 < 8)       stage_oct(bhq, o + 1);
      else if (q + 1 < Qq) stage_oct(bhq + 32768, 0);
      // (loads fly under collection and phases C/D/A)

      // sparse shared-min update (octs 0,3,7): 4 chains x 4 shfl steps
      if (o == 0 || o == 3 || o == 7) {
#pragma unroll
        for (int r = 0; r < 4; ++r) {
          float v = min8[r];
#pragma unroll
          for (int m = 1; m < 16; m <<= 1) {
            const float ov = __shfl_xor(v, m);
            v = ov < v ? ov : v;
          }
          if (col == 0)
            atomicMin(&runm_sh[tg * 16 + g4 * 4 + r], fenc(v));
        }
      }

      // collect vs (possibly lagged) shared min: superset of the validated
      // prefix-min margin rule -> exact winner always collected.
#pragma unroll
      for (int jt = 0; jt < 4; ++jt)
#pragma unroll
        for (int r = 0; r < 4; ++r) {
          const int t = tg * 16 + g4 * 4 + r;
          if (s[jt][r] <= fdec(runm_sh[t]) + MARGIN) {
            const int pos = atomicAdd(&cnt[t], 1);
            if (pos < LCAP) list[t][pos] = (o * 8 + h * 4 + jt) * 16 + col;
          }
        }
    }
    __syncthreads();                             // lists complete

    // ---- phase C: parallel rescue — 8 threads per token, candidate-sliced.
    {
      const int t    = tid >> 3;
      const int slot = tid & 7;
      const int sw   = t & 7;
      const int c_   = cnt[t];
      float best = 3.4e38f;
      int   wdx  = 1 << 30;
      if (c_ == 1) {
        wdx = list[t][0];
        best = 0.0f;                             // uniform across the 8 slots
      } else if (c_ <= LCAP) {
        for (int it = slot; it < c_; it += 8) {
          const int cand = list[t][it];
          const float sc = exact_score_lds(tile, t, sw, cb, cn_, cand);
          if (sc < best || (sc == best && cand < wdx)) { best = sc; wdx = cand; }
        }
      } else {        // overflow safety net: full exact scan, candidate-sliced
        for (int cand = slot; cand < Cc; cand += 8) {
          const float sc = exact_score_lds(tile, t, sw, cb, cn_, cand);
          if (sc < best || (sc == best && cand < wdx)) { best = sc; wdx = cand; }
        }
      }
#pragma unroll
      for (int m = 1; m < 8; m <<= 1) {
        const float ov = __shfl_xor(best, m);
        const int   oi = __shfl_xor(wdx, m);
        if (ov < best || (ov == best && oi < wdx)) { best = ov; wdx = oi; }
      }
      if (slot == 0) {
        win[t] = wdx;
        idx_out[(size_t)(tok0 + t) * Qq + q] = (float)wdx;
      }
    }
    __syncthreads();

    // ---- phase D: epilogue — update residual tile in place + loss.
    //   e = q - r; q_st = r + e; r_new = r - q_st; loss += e^2
    float lsum = 0.0f;
    {
      const float4* cb4 = reinterpret_cast<const float4*>(cb);
#pragma unroll
      for (int k = 0; k < 8; ++k) {
        const int j = tid + k * NT;
        const int tk = j >> 6, d4 = j & 63;
        const int widx = win[tk];
        const float4 cv = cb4[(size_t)widx * 64 + d4];
        const float4 rv = tile[(tk * 64 + d4) ^ (tk & 7)];
        const float ex = cv.x - rv.x, ey = cv.y - rv.y, ez = cv.z - rv.z, ew = cv.w - rv.w;
        const float qsx = rv.x + ex, qsy = rv.y + ey, qsz = rv.z + ez, qsw = rv.w + ew;
        lsum += ex * ex + ey * ey + ez * ez + ew * ew;
        tile[(tk * 64 + d4) ^ (tk & 7)] =
            make_float4(rv.x - qsx, rv.y - qsy, rv.z - qsz, rv.w - qsw);
      }
    }
#pragma unroll
    for (int s = 32; s; s >>= 1) lsum += __shfl_xor(lsum, s);
    if (lane == 0) atomicAdd(&loss_acc[q], lsum);
    __syncthreads();     // tile updated before next stage / final out
  }

  // ---- final: qout = x - r_final (telescoped straight-through sum), coalesced
  {
    float4* qo = reinterpret_cast<float4*>(qout + (size_t)tok0 * Dd);
#pragma unroll
    for (int k = 0; k < 8; ++k) {
      const int j = tid + k * NT;
      const int tk = j >> 6, d4 = j & 63;
      const float4 xv = xs[j];
      const float4 rv = tile[(tk * 64 + d4) ^ (tk & 7)];
      qo[j] = make_float4(xv.x - rv.x, xv.y - rv.y, xv.z - rv.z, xv.w - rv.w);
    }
  }
}

// ---------------------------------------------------------------------------
__global__ void finalize_losses(const float* __restrict__ loss_acc,
                                float* __restrict__ loss_out) {
  if (threadIdx.x < Qq) loss_out[threadIdx.x] = loss_acc[threadIdx.x] * (1.0f / (float)(Mm * Dd));
}

extern "C" void kernel_launch(void* const* d_in, const int* in_sizes, int n_in,
                              void* d_out, int out_size, void* d_ws, size_t ws_size,
                              hipStream_t stream) {
  const float* x   = (const float*)d_in[0];   // [B,N,D]
  const float* cbs = (const float*)d_in[1];   // [Q,C,D]
  float* out      = (float*)d_out;
  float* qout     = out;                               // M*D
  float* idx_out  = out + (size_t)Mm * Dd;             // M*Q
  float* loss_out = idx_out + (size_t)Mm * Qq;         // Q

  char* w = (char*)d_ws;
  short* Bh       = (short*)w;                                  // 4 MB
  float* cnorm    = (float*)(w + (size_t)4194304);              // 32 KB
  float* loss_acc = (float*)(w + (size_t)4227072);              // 256 B

  prep_kernel<<<(Qq * Cc) / 4, 256, 0, stream>>>(cbs, cnorm, loss_acc);
  build_bfrag<<<Qq * 64, 256, 0, stream>>>(cbs, Bh);

  vq_fused<<<Mm / TOK, NT, 0, stream>>>(cbs, (const short8*)Bh,
                                        cnorm, x, qout, idx_out, loss_acc);

  finalize_losses<<<1, 64, 0, stream>>>(loss_acc, loss_out);
}